// Round 8
// baseline (256.902 us; speedup 1.0000x reference)
//
#include <hip/hip_runtime.h>
#include <cstdint>

namespace {

constexpr int W = 256;
constexpr int ITERS = 10;
constexpr int PSTR = 260;   // fpart row stride (floats)

// R15: TWO CO-RESIDENT BLOCKS PER CU, SINGLE ROUND.
// R14 post-mortem: VALUBusy 39% with 2 waves/SIMD and the whole 512-reg
// pool eaten by one block -> 61% of cycles nothing can issue (barriers,
// LDS round-trips, dep chains). Fix occupancy, not instructions:
//   512 thr, waves_per_eu(4,4) => <=128 unified regs/thread;
//   E split 12 rows in regs (96 fl) + 4 rows in XOR-swizzled LDS (64 KB);
//   eul moved to LDS (in-wave write/read, no extra barrier);
//   row pass chunked by 4 rows to cap rp liveness (peak live ~124);
//   LDS/block ~74.2 KB -> 2 blocks/CU -> 480 blocks all resident, the
//   120 MB load burst overlaps compute across blocks; prefetch deleted.
template <int CTRL>
__device__ __forceinline__ float dpp_add(float x) {
  int y = __builtin_amdgcn_mov_dpp(__float_as_int(x), CTRL, 0xF, 0xF, true);
  return x + __int_as_float(y);
}
template <int PAT>
__device__ __forceinline__ float swz_add(float x) {
  return x + __int_as_float(__builtin_amdgcn_ds_swizzle(__float_as_int(x), PAT));
}
__device__ __forceinline__ float allred32(float x) {  // sum over 32-lane group
  x = dpp_add<0xB1>(x);    // quad_perm xor1
  x = dpp_add<0x4E>(x);    // quad_perm xor2
  x = dpp_add<0x141>(x);   // row_half_mirror = xor7 (span now 0..7)
  x = dpp_add<0x140>(x);   // row_mirror = xor15 (span now 0..15)
  x = swz_add<0x401F>(x);  // xor16 (span 0..31)
  return x;
}
__device__ __forceinline__ float rcpf(float x) {
  float r;
  asm("v_rcp_f32 %0, %1" : "=v"(r) : "v"(x));
  return r;
}

__global__ __launch_bounds__(512)
__attribute__((amdgpu_waves_per_eu(4, 4)))
void sinkhorn_disp_kernel(
    const float* __restrict__ attn,
    const float* __restrict__ phi_p,
    float* __restrict__ out,
    int nh)
{
  __shared__ __align__(16) float E_lds[512 * 32];  // 64 KB: rows 12..15
  __shared__ __align__(16) float fpart[8][PSTR];   // 8.3 KB col partials
  __shared__ __align__(16) float ev_l[W];          // swizzled ev
  __shared__ __align__(16) float eul_l[W];         // eu by row (plain layout)
  __shared__ __align__(16) float seup[16];         // per-rg sum(eu)

  const int tid  = threadIdx.x;
  const int lane = tid & 63;
  const int wid  = tid >> 6;                 // wave 0..7
  const int cg   = lane & 31;                // col group: cols [8cg, 8cg+8)
  const int rg   = 2 * wid + (lane >> 5);    // row group: rows [16rg, +16)
  const int bid  = blockIdx.x;
  const int sw   = tid & 7;                  // E-chunk swizzle key
  float* myE = &E_lds[tid * 32];
  // chunk c (0..7) <-> tile row 12+(c>>1), col half c&1 (thread-private)
  #define RDCH(c) (*(const float4*)&myE[4 * ((c) ^ sw)])

  // swizzled float offset of this thread's first 16B chunk of a 256-f row:
  // chunk c = 2cg+h -> c' = c ^ ((cg>>2)&7); second chunk = ch0 ^ (4 floats)
  const int ch0 = 4 * ((2 * cg) ^ ((cg >> 2) & 7));

  const float ephi = __int_as_float(
      __builtin_amdgcn_readfirstlane(__float_as_int(__expf(phi_p[0]))));
  const float inv2w = 1.0f / (2.0f * W);

  // ---- load + exp: rows 0..11 -> registers, rows 12..15 -> swizzled LDS --
  float Er[12][8];
  {
    const float* src = attn + (size_t)bid * (W * W)
                     + (size_t)(rg * 16) * W + cg * 8;
    #pragma unroll
    for (int r = 0; r < 12; ++r) {
      float4 x0 = *(const float4*)(src + r * W);
      float4 x1 = *(const float4*)(src + r * W + 4);
      Er[r][0] = __expf(x0.x); Er[r][1] = __expf(x0.y);
      Er[r][2] = __expf(x0.z); Er[r][3] = __expf(x0.w);
      Er[r][4] = __expf(x1.x); Er[r][5] = __expf(x1.y);
      Er[r][6] = __expf(x1.z); Er[r][7] = __expf(x1.w);
    }
    #pragma unroll
    for (int r = 0; r < 4; ++r) {            // rows 12..15 -> chunks 2r,2r+1
      float4 x0 = *(const float4*)(src + (12 + r) * W);
      float4 x1 = *(const float4*)(src + (12 + r) * W + 4);
      *(float4*)&myE[4 * ((2 * r)     ^ sw)] =
          make_float4(__expf(x0.x), __expf(x0.y), __expf(x0.z), __expf(x0.w));
      *(float4*)&myE[4 * ((2 * r + 1) ^ sw)] =
          make_float4(__expf(x1.x), __expf(x1.y), __expf(x1.z), __expf(x1.w));
    }
  }
  // init eu = 1 : in-wave (each half-wave writes its own 16 rows)
  if (cg < 16) eul_l[16 * rg + cg] = 1.0f;
  float euW  = 1.0f;
  float evWk = 0.0f;

  for (int it = 0; it < ITERS; ++it) {
    // ---- col pass: cp[b] = sum_r E[16rg+r][8cg+b] * eu[16rg+r] ----
    {
      float cp[8];
      #pragma unroll
      for (int b = 0; b < 8; ++b) cp[b] = 0.0f;
      float sSeu = 0.0f;
      #pragma unroll
      for (int q = 0; q < 3; ++q) {          // reg rows 0..11
        float4 u4 = *(const float4*)&eul_l[16 * rg + 4 * q];  // broadcast
        sSeu += ((u4.x + u4.y) + (u4.z + u4.w));
        float uu[4] = {u4.x, u4.y, u4.z, u4.w};
        #pragma unroll
        for (int k = 0; k < 4; ++k) {
          #pragma unroll
          for (int b = 0; b < 8; ++b)
            cp[b] = __builtin_fmaf(Er[4 * q + k][b], uu[k], cp[b]);
        }
      }
      {                                       // LDS rows 12..15
        float4 u4 = *(const float4*)&eul_l[16 * rg + 12];
        sSeu += ((u4.x + u4.y) + (u4.z + u4.w));
        float uu[4] = {u4.x, u4.y, u4.z, u4.w};
        #pragma unroll
        for (int r = 0; r < 4; ++r) {
          float4 e0 = RDCH(2 * r), e1 = RDCH(2 * r + 1);
          float ua = uu[r];
          cp[0] = __builtin_fmaf(e0.x, ua, cp[0]);
          cp[1] = __builtin_fmaf(e0.y, ua, cp[1]);
          cp[2] = __builtin_fmaf(e0.z, ua, cp[2]);
          cp[3] = __builtin_fmaf(e0.w, ua, cp[3]);
          cp[4] = __builtin_fmaf(e1.x, ua, cp[4]);
          cp[5] = __builtin_fmaf(e1.y, ua, cp[5]);
          cp[6] = __builtin_fmaf(e1.z, ua, cp[6]);
          cp[7] = __builtin_fmaf(e1.w, ua, cp[7]);
        }
      }
      // combine rg-parity pair (lane <-> lane^32: same cg, rg 2w/2w+1)
      #pragma unroll
      for (int b = 0; b < 8; ++b) cp[b] += __shfl_xor(cp[b], 32, 64);
      if (lane < 32) {   // conflict-free b128 writes (chunk XOR swizzle)
        *(float4*)&fpart[wid][ch0    ] = make_float4(cp[0], cp[1], cp[2], cp[3]);
        *(float4*)&fpart[wid][ch0 ^ 4] = make_float4(cp[4], cp[5], cp[6], cp[7]);
      }
      if ((lane & 31) == 0) seup[rg] = sSeu;
    }
    __syncthreads();                       // barrier 1
    // ---- finalize ev: 512 threads, pair (2k,2k+1) splits the 8 groups ----
    {
      const int j  = tid >> 1;
      const int fj = ((((j >> 2) ^ ((j >> 5) & 7)) << 2) | (j & 3));
      const int g0 = (tid & 1) * 4;
      float s = (fpart[g0][fj] + fpart[g0 + 1][fj])
              + (fpart[g0 + 2][fj] + fpart[g0 + 3][fj]);
      s = dpp_add<0xB1>(s);                // pair-combine (same j)
      if (!(tid & 1)) ev_l[fj] = inv2w * rcpf(s + ephi * euW);
      // every thread: evW from seup (read is safe only inside this window)
      float4 s0 = *(const float4*)&seup[0];
      float4 s1 = *(const float4*)&seup[4];
      float4 s2 = *(const float4*)&seup[8];
      float4 s3 = *(const float4*)&seup[12];
      float Seu = ((((s0.x + s0.y) + (s0.z + s0.w))
                  + ((s1.x + s1.y) + (s1.z + s1.w)))
                 + (((s2.x + s2.y) + (s2.z + s2.w))
                  + ((s3.x + s3.y) + (s3.z + s3.w))));
      evWk = 0.5f * rcpf(ephi * (Seu + euW));
    }
    __syncthreads();                       // barrier 2
    // ---- row pass: chunks of 4 rows; eul written to LDS in-wave ----
    {
      float4 v0 = *(const float4*)&ev_l[ch0];
      float4 v1 = *(const float4*)&ev_l[ch0 ^ 4];
      float vl[8] = {v0.x, v0.y, v0.z, v0.w, v1.x, v1.y, v1.z, v1.w};
      const float eAdd = ephi * evWk;
      #pragma unroll
      for (int q = 0; q < 3; ++q) {          // reg rows 0..11
        float rp[4];
        #pragma unroll
        for (int k = 0; k < 4; ++k) {
          float s = 0.0f;
          #pragma unroll
          for (int b = 0; b < 8; ++b)
            s = __builtin_fmaf(Er[4 * q + k][b], vl[b], s);
          rp[k] = s;
        }
        #pragma unroll
        for (int k = 0; k < 4; ++k) rp[k] = allred32(rp[k]);
        float wv = rp[0];
        wv = (cg == 1) ? rp[1] : wv;
        wv = (cg == 2) ? rp[2] : wv;
        wv = (cg == 3) ? rp[3] : wv;
        if (cg < 4) eul_l[16 * rg + 4 * q + cg] = inv2w * rcpf(wv + eAdd);
      }
      {                                       // LDS rows 12..15
        float rp[4];
        #pragma unroll
        for (int r = 0; r < 4; ++r) {
          float4 e0 = RDCH(2 * r), e1 = RDCH(2 * r + 1);
          rp[r] = e0.x * vl[0] + e0.y * vl[1] + e0.z * vl[2] + e0.w * vl[3]
                + e1.x * vl[4] + e1.y * vl[5] + e1.z * vl[6] + e1.w * vl[7];
        }
        #pragma unroll
        for (int k = 0; k < 4; ++k) rp[k] = allred32(rp[k]);
        float wv = rp[0];
        wv = (cg == 1) ? rp[1] : wv;
        wv = (cg == 2) ? rp[2] : wv;
        wv = (cg == 3) ? rp[3] : wv;
        if (cg < 4) eul_l[16 * rg + 12 + cg] = inv2w * rcpf(wv + eAdd);
      }
      float sev = ((vl[0] + vl[1]) + (vl[2] + vl[3]))
                + ((vl[4] + vl[5]) + (vl[6] + vl[7]));
      sev = allred32(sev);
      euW = 0.5f * rcpf(ephi * (sev + evWk));
    }
  }

  // ---- finale: per-row argmax + 3-tap window, all in-half-wave ----
  float vl[8];
  {
    float4 v0 = *(const float4*)&ev_l[ch0];
    float4 v1 = *(const float4*)&ev_l[ch0 ^ 4];
    vl[0] = v0.x; vl[1] = v0.y; vl[2] = v0.z; vl[3] = v0.w;
    vl[4] = v1.x; vl[5] = v1.y; vl[6] = v1.z; vl[7] = v1.w;
  }
  float res_disp = 0.0f, res_occ = 0.0f;
  #pragma unroll
  for (int r = 0; r < 16; ++r) {
    float v[8];
    if (r < 12) {
      #pragma unroll
      for (int b = 0; b < 8; ++b) v[b] = Er[r < 12 ? r : 0][b] * vl[b];
    } else {
      float4 e0 = RDCH(2 * (r - 12)), e1 = RDCH(2 * (r - 12) + 1);
      v[0] = e0.x * vl[0]; v[1] = e0.y * vl[1];
      v[2] = e0.z * vl[2]; v[3] = e0.w * vl[3];
      v[4] = e1.x * vl[4]; v[5] = e1.y * vl[5];
      v[6] = e1.z * vl[6]; v[7] = e1.w * vl[7];
    }
    float m = v[0]; int mj = cg * 8;
    #pragma unroll
    for (int b = 1; b < 8; ++b) {
      if (v[b] > m) { m = v[b]; mj = cg * 8 + b; }   // strict >: first max
    }
    // pack (value, first-index-wins); values > 0 so float bits order-preserve
    unsigned long long best =
        (((unsigned long long)__float_as_uint(m)) << 32) |
        (unsigned)(65535 - mj);
    #pragma unroll
    for (int off = 16; off > 0; off >>= 1) {
      unsigned long long o = __shfl_xor(best, off, 32);
      if (o > best) best = o;
    }
    const int jm = 65535 - (int)(best & 0xffffffffull);
    const int i  = rg * 16 + r;
    const float us = eul_l[i] * (2.0f * W);   // in-wave broadcast read
    float num = 0.0f, den = 0.0f;
    #pragma unroll
    for (int b = 0; b < 8; ++b) {
      int j = cg * 8 + b;
      if (j >= jm - 1 && j <= jm + 1) {
        float wv = v[b] * us;
        den += wv;
        num += wv * fmaxf((float)(i - j), 0.0f);
      }
    }
    den = allred32(den);
    num = allred32(num);
    if (cg == r) {                         // lane r of the half-wave keeps row r
      float norm = (den < 0.1f) ? 1.0f : den;
      res_disp = num / norm;
      res_occ  = 1.0f - norm;
    }
  }
  if (cg < 16) {
    const int i = rg * 16 + cg;
    out[(size_t)bid * W + i] = res_disp;
    out[(size_t)nh * W + (size_t)bid * W + i] = res_occ;
  }
  #undef RDCH
}

} // namespace

extern "C" void kernel_launch(void* const* d_in, const int* in_sizes, int n_in,
                              void* d_out, int out_size, void* d_ws, size_t ws_size,
                              hipStream_t stream) {
  (void)n_in; (void)d_ws; (void)ws_size; (void)out_size;
  const float* attn = (const float*)d_in[0];
  const float* phi  = (const float*)d_in[1];
  float* out = (float*)d_out;
  const int nh = in_sizes[0] / (W * W);   // 4*120 = 480 matrices
  sinkhorn_disp_kernel<<<dim3(nh), dim3(512), 0, stream>>>(attn, phi, out, nh);
}

// Round 9
// 234.790 us; speedup vs baseline: 1.0942x; 1.0942x over previous
//
#include <hip/hip_runtime.h>
#include <cstdint>

namespace {

constexpr int W = 256;
constexpr int ITERS = 10;
constexpr int PSTR = 260;   // fpart row stride (floats)

// R16 = R14 with the synchronization structure cut in half:
//   - finalize phase MERGED into the row pass: each thread reduces the 8
//     group-partials for its OWN 8 columns directly from fpart (16 b128
//     reads + 14 f4-adds + 8 rcp) instead of a separate 512-thread
//     finalize + ev LDS broadcast.
//   - fpart/seup double-buffered -> ONE barrier per iteration (was 2).
//     Race-free: a wave cannot reach iter k+2's writes of buffer p without
//     every wave passing iter k+1's barrier (which postdates all reads
//     of p at iter k).
//   - ev never materialized in LDS; own-col ev (vl) stays in registers
//     through the finale. Barriers: 20 -> 10 per kernel.
// R15 post-mortem pinned: occupancy-via-register-squeeze spills (the
// allocator needs ~40-50 regs above hand-audit); stay at waves_per_eu(2,2),
// 512 thr, whole matrix in regs/AGPRs (R14 storage).
template <int CTRL>
__device__ __forceinline__ float dpp_add(float x) {
  int y = __builtin_amdgcn_mov_dpp(__float_as_int(x), CTRL, 0xF, 0xF, true);
  return x + __int_as_float(y);
}
template <int PAT>
__device__ __forceinline__ float swz_add(float x) {
  return x + __int_as_float(__builtin_amdgcn_ds_swizzle(__float_as_int(x), PAT));
}
__device__ __forceinline__ float allred32(float x) {  // sum over 32-lane group
  x = dpp_add<0xB1>(x);    // quad_perm xor1
  x = dpp_add<0x4E>(x);    // quad_perm xor2
  x = dpp_add<0x141>(x);   // row_half_mirror = xor7
  x = dpp_add<0x140>(x);   // row_mirror = xor15
  x = swz_add<0x401F>(x);  // xor16 (span 0..31)
  return x;
}
__device__ __forceinline__ float rcpf(float x) {
  float r;
  asm("v_rcp_f32 %0, %1" : "=v"(r) : "v"(x));
  return r;
}
__device__ __forceinline__ float4 f4add(float4 a, float4 b) {
  return make_float4(a.x + b.x, a.y + b.y, a.z + b.z, a.w + b.w);
}

__global__ __launch_bounds__(512)
__attribute__((amdgpu_waves_per_eu(2, 2)))
void sinkhorn_disp_kernel(
    const float* __restrict__ attn,
    const float* __restrict__ phi_p,
    float* __restrict__ out,
    int nh)
{
  __shared__ __align__(16) float fpart[2][8][PSTR];  // dbuf col partials
  __shared__ __align__(16) float seup[2][16];        // dbuf per-rg sum(eu)

  const int tid  = threadIdx.x;
  const int lane = tid & 63;
  const int wid  = tid >> 6;                 // wave 0..7
  const int cg   = lane & 31;                // col group: cols [8cg, 8cg+8)
  const int rg   = 2 * wid + (lane >> 5);    // row group: rows [16rg, +16)
  const int bid  = blockIdx.x;

  // swizzled float offset of this thread's first 16B chunk of a 256-f row:
  // chunk c = 2cg+h -> c' = c ^ ((cg>>2)&7); second chunk = ch0 ^ (4 floats)
  const int ch0 = 4 * ((2 * cg) ^ ((cg >> 2) & 7));

  const float ephi = __int_as_float(
      __builtin_amdgcn_readfirstlane(__float_as_int(__expf(phi_p[0]))));
  const float inv2w = 1.0f / (2.0f * W);

  // ---- load + exp: ALL 16 rows -> registers ----
  float Er[16][8];
  {
    const float* src = attn + (size_t)bid * (W * W)
                     + (size_t)(rg * 16) * W + cg * 8;
    #pragma unroll
    for (int r = 0; r < 16; ++r) {
      float4 x0 = *(const float4*)(src + r * W);
      float4 x1 = *(const float4*)(src + r * W + 4);
      Er[r][0] = __expf(x0.x); Er[r][1] = __expf(x0.y);
      Er[r][2] = __expf(x0.z); Er[r][3] = __expf(x0.w);
      Er[r][4] = __expf(x1.x); Er[r][5] = __expf(x1.y);
      Er[r][6] = __expf(x1.z); Er[r][7] = __expf(x1.w);
    }
  }

  float eul[16];
  #pragma unroll
  for (int r = 0; r < 16; ++r) eul[r] = 1.0f;   // u0 = 0 -> eu = 1
  float euW = 1.0f;
  float vl[8];                               // own-col ev; live into finale
  #pragma unroll
  for (int b = 0; b < 8; ++b) vl[b] = 0.0f;

  const bool  do_pf = (bid + 256 < nh);
  const float* pfp  = attn + (size_t)(bid + 256) * (W * W) + (size_t)tid * 16;
  float pfv = 0.0f;

  for (int it = 0; it < ITERS; ++it) {
    const int p = it & 1;
    // ---- L3/L2 prefetch of matrix bid+256: issue now, consume at iter end
    if (do_pf && it < 8)
      pfv = pfp[(size_t)it * (512 * 16)];        // 1 float per 64B line
    // ---- col pass: cp[b] = sum_r E[16rg+r][8cg+b] * eu[16rg+r] ----
    {
      float cp[8];
      #pragma unroll
      for (int b = 0; b < 8; ++b) cp[b] = 0.0f;
      #pragma unroll
      for (int r = 0; r < 16; ++r) {
        float u = eul[r];
        #pragma unroll
        for (int b = 0; b < 8; ++b)
          cp[b] = __builtin_fmaf(Er[r][b], u, cp[b]);
      }
      // combine rg-parity pair (lane <-> lane^32: same cg, rg 2w/2w+1)
      #pragma unroll
      for (int b = 0; b < 8; ++b) cp[b] += __shfl_xor(cp[b], 32, 64);
      if (lane < 32) {   // conflict-free b128 writes (chunk XOR swizzle)
        *(float4*)&fpart[p][wid][ch0    ] = make_float4(cp[0], cp[1], cp[2], cp[3]);
        *(float4*)&fpart[p][wid][ch0 ^ 4] = make_float4(cp[4], cp[5], cp[6], cp[7]);
      }
      if ((lane & 31) == 0) {
        float s = (((eul[0] + eul[1]) + (eul[2] + eul[3]))
                 + ((eul[4] + eul[5]) + (eul[6] + eul[7])))
                + (((eul[8] + eul[9]) + (eul[10] + eul[11]))
                 + ((eul[12] + eul[13]) + (eul[14] + eul[15])));
        seup[p][rg] = s;
      }
    }
    __syncthreads();                       // THE barrier (1 per iteration)
    // ---- merged finalize + row pass ----
    {
      // own-col group-partial reduction: 16 b128 reads, 4-way-floor banks
      float4 A0 = *(const float4*)&fpart[p][0][ch0];
      float4 A1 = *(const float4*)&fpart[p][1][ch0];
      float4 A2 = *(const float4*)&fpart[p][2][ch0];
      float4 A3 = *(const float4*)&fpart[p][3][ch0];
      float4 A4 = *(const float4*)&fpart[p][4][ch0];
      float4 A5 = *(const float4*)&fpart[p][5][ch0];
      float4 A6 = *(const float4*)&fpart[p][6][ch0];
      float4 A7 = *(const float4*)&fpart[p][7][ch0];
      float4 sa = f4add(f4add(f4add(A0, A1), f4add(A2, A3)),
                        f4add(f4add(A4, A5), f4add(A6, A7)));
      float4 B0 = *(const float4*)&fpart[p][0][ch0 ^ 4];
      float4 B1 = *(const float4*)&fpart[p][1][ch0 ^ 4];
      float4 B2 = *(const float4*)&fpart[p][2][ch0 ^ 4];
      float4 B3 = *(const float4*)&fpart[p][3][ch0 ^ 4];
      float4 B4 = *(const float4*)&fpart[p][4][ch0 ^ 4];
      float4 B5 = *(const float4*)&fpart[p][5][ch0 ^ 4];
      float4 B6 = *(const float4*)&fpart[p][6][ch0 ^ 4];
      float4 B7 = *(const float4*)&fpart[p][7][ch0 ^ 4];
      float4 sb = f4add(f4add(f4add(B0, B1), f4add(B2, B3)),
                        f4add(f4add(B4, B5), f4add(B6, B7)));
      // Seu (broadcast reads) -> evW ; ev for own 8 cols (uses OLD euW)
      float4 s0 = *(const float4*)&seup[p][0];
      float4 s1 = *(const float4*)&seup[p][4];
      float4 s2 = *(const float4*)&seup[p][8];
      float4 s3 = *(const float4*)&seup[p][12];
      float Seu = ((((s0.x + s0.y) + (s0.z + s0.w))
                  + ((s1.x + s1.y) + (s1.z + s1.w)))
                 + (((s2.x + s2.y) + (s2.z + s2.w))
                  + ((s3.x + s3.y) + (s3.z + s3.w))));
      const float evW = 0.5f * rcpf(ephi * (Seu + euW));
      const float eW  = ephi * euW;
      vl[0] = inv2w * rcpf(sa.x + eW);
      vl[1] = inv2w * rcpf(sa.y + eW);
      vl[2] = inv2w * rcpf(sa.z + eW);
      vl[3] = inv2w * rcpf(sa.w + eW);
      vl[4] = inv2w * rcpf(sb.x + eW);
      vl[5] = inv2w * rcpf(sb.y + eW);
      vl[6] = inv2w * rcpf(sb.z + eW);
      vl[7] = inv2w * rcpf(sb.w + eW);
      // row pass: rp[r] = sum_b E[r][b]*ev[b], allreduce over 32 lanes
      float rp[16];
      #pragma unroll
      for (int r = 0; r < 16; ++r) {
        float s = 0.0f;
        #pragma unroll
        for (int b = 0; b < 8; ++b)
          s = __builtin_fmaf(Er[r][b], vl[b], s);
        rp[r] = s;
      }
      float sev = ((vl[0] + vl[1]) + (vl[2] + vl[3]))
                + ((vl[4] + vl[5]) + (vl[6] + vl[7]));
      #pragma unroll
      for (int r = 0; r < 16; ++r) rp[r] = allred32(rp[r]);
      sev = allred32(sev);
      const float eAdd = ephi * evW;
      #pragma unroll
      for (int r = 0; r < 16; ++r) eul[r] = inv2w * rcpf(rp[r] + eAdd);
      euW = 0.5f * rcpf(ephi * (sev + evW));
    }
    // ---- consume the prefetch issued at iter top ----
    if (do_pf && it < 8) asm volatile("" :: "v"(pfv));
  }

  // ---- finale: per-row argmax + 3-tap window, all in-half-wave ----
  // vl[] already holds ev for this thread's 8 cols (from the last row pass).
  float res_disp = 0.0f, res_occ = 0.0f;
  #pragma unroll
  for (int r = 0; r < 16; ++r) {
    float v[8];
    #pragma unroll
    for (int b = 0; b < 8; ++b) v[b] = Er[r][b] * vl[b];
    float m = v[0]; int mj = cg * 8;
    #pragma unroll
    for (int b = 1; b < 8; ++b) {
      if (v[b] > m) { m = v[b]; mj = cg * 8 + b; }   // strict >: first max
    }
    // pack (value, first-index-wins); values > 0 so float bits order-preserve
    unsigned long long best =
        (((unsigned long long)__float_as_uint(m)) << 32) |
        (unsigned)(65535 - mj);
    #pragma unroll
    for (int off = 16; off > 0; off >>= 1) {
      unsigned long long o = __shfl_xor(best, off, 32);
      if (o > best) best = o;
    }
    const int jm = 65535 - (int)(best & 0xffffffffull);
    const int i  = rg * 16 + r;
    const float us = eul[r] * (2.0f * W);
    float num = 0.0f, den = 0.0f;
    #pragma unroll
    for (int b = 0; b < 8; ++b) {
      int j = cg * 8 + b;
      if (j >= jm - 1 && j <= jm + 1) {
        float wv = v[b] * us;
        den += wv;
        num += wv * fmaxf((float)(i - j), 0.0f);
      }
    }
    den = allred32(den);
    num = allred32(num);
    if (cg == r) {                         // lane r of the half-wave keeps row r
      float norm = (den < 0.1f) ? 1.0f : den;
      res_disp = num / norm;
      res_occ  = 1.0f - norm;
    }
  }
  if (cg < 16) {
    const int i = rg * 16 + cg;
    out[(size_t)bid * W + i] = res_disp;
    out[(size_t)nh * W + (size_t)bid * W + i] = res_occ;
  }
}

} // namespace

extern "C" void kernel_launch(void* const* d_in, const int* in_sizes, int n_in,
                              void* d_out, int out_size, void* d_ws, size_t ws_size,
                              hipStream_t stream) {
  (void)n_in; (void)d_ws; (void)ws_size; (void)out_size;
  const float* attn = (const float*)d_in[0];
  const float* phi  = (const float*)d_in[1];
  float* out = (float*)d_out;
  const int nh = in_sizes[0] / (W * W);   // 4*120 = 480 matrices
  sinkhorn_disp_kernel<<<dim3(nh), dim3(512), 0, stream>>>(attn, phi, out, nh);
}